// Round 1
// baseline (79.615 us; speedup 1.0000x reference)
//
#include <hip/hip_runtime.h>

// ConditionalDense: out[b,u] = sum_d x[b,d]*kernel[cls[b],d,u] + bias[cls[b],u]
// B=2048, D=512, U=512, C=100, all float32.
// Strategy: device-side counting sort by class, then class-chunked batched matvec.

constexpr int C_CLS   = 100;
constexpr int B_N     = 2048;
constexpr int D_DIM   = 512;
constexpr int U_DIM   = 512;
constexpr int S_CHUNK = 8;     // samples per chunk (padding granularity)
constexpr int MAX_CHUNKS = 360; // >= max possible sum(ceil(n_c/S)) = 256 + 87 = 343
constexpr int TU      = 256;   // u-columns per block (64 threads x 4 u each)

// ---------------- sort kernels ----------------

__global__ void k_init(int* ws) {
    // zero counts[0:128) and cursor[128:256)
    ws[threadIdx.x] = 0;
}

__global__ void k_hist(const int* __restrict__ cls, int* __restrict__ counts) {
    int i = blockIdx.x * blockDim.x + threadIdx.x;
    if (i < B_N) atomicAdd(&counts[cls[i]], 1);
}

__global__ void k_scan(const int* __restrict__ counts, int* __restrict__ offsets,
                       int* __restrict__ total_chunks, int* __restrict__ chunk_cls,
                       int* __restrict__ chunk_start, int* __restrict__ chunk_len) {
    __shared__ int s_off[128], s_chk[128];
    int tid = threadIdx.x;
    int cnt = (tid < C_CLS) ? counts[tid] : 0;
    int nch = (cnt + S_CHUNK - 1) / S_CHUNK;
    s_off[tid] = cnt; s_chk[tid] = nch;
    __syncthreads();
    // Hillis-Steele inclusive scan over 128 elements
    for (int st = 1; st < 128; st <<= 1) {
        int a = 0, b = 0;
        if (tid >= st) { a = s_off[tid - st]; b = s_chk[tid - st]; }
        __syncthreads();
        s_off[tid] += a; s_chk[tid] += b;
        __syncthreads();
    }
    if (tid < C_CLS) {
        int off = s_off[tid] - cnt;   // exclusive prefix of counts
        int cb  = s_chk[tid] - nch;   // exclusive prefix of chunk counts
        offsets[tid] = off;
        for (int j = 0; j < nch; ++j) {
            chunk_cls[cb + j]   = tid;
            chunk_start[cb + j] = off + j * S_CHUNK;
            chunk_len[cb + j]   = min(S_CHUNK, cnt - j * S_CHUNK);
        }
    }
    if (tid == 0)   offsets[C_CLS] = B_N;
    if (tid == 127) *total_chunks = s_chk[127];
}

__global__ void k_scatter(const int* __restrict__ cls, const int* __restrict__ offsets,
                          int* __restrict__ cursor, int* __restrict__ order) {
    int i = blockIdx.x * blockDim.x + threadIdx.x;
    if (i < B_N) {
        int c = cls[i];
        int p = atomicAdd(&cursor[c], 1);
        order[offsets[c] + p] = i;
    }
}

// ---------------- main kernel ----------------
// grid: (MAX_CHUNKS, U_DIM/TU), block: 64 threads.
// Each block: one chunk (<=8 same-class samples) x one 256-wide u-tile.
// Thread t owns u = blockIdx.y*256 + t*4 .. +3 (float4 W loads, coalesced).

__launch_bounds__(64)
__global__ void k_main(const float* __restrict__ x, const float* __restrict__ kern,
                       const float* __restrict__ bias, const int* __restrict__ order,
                       const int* __restrict__ total_chunks,
                       const int* __restrict__ chunk_cls,
                       const int* __restrict__ chunk_start,
                       const int* __restrict__ chunk_len,
                       float* __restrict__ out) {
    int chunk = blockIdx.x;
    if (chunk >= *total_chunks) return;
    int tid   = threadIdx.x;
    int c     = chunk_cls[chunk];
    int start = chunk_start[chunk];
    int len   = chunk_len[chunk];

    __shared__ int   sidx[S_CHUNK];
    __shared__ float xs[S_CHUNK][D_DIM];

    if (tid < S_CHUNK) sidx[tid] = (tid < len) ? order[start + tid] : -1;
    __syncthreads();

    // stage x rows for the chunk: 8 * 128 float4 = 1024 loads / 64 threads
    for (int i = tid; i < S_CHUNK * (D_DIM / 4); i += 64) {
        int s = i >> 7;     // /128
        int f = i & 127;
        int b = sidx[s];
        float4 v = make_float4(0.f, 0.f, 0.f, 0.f);
        if (b >= 0) v = reinterpret_cast<const float4*>(x)[b * (D_DIM / 4) + f];
        reinterpret_cast<float4*>(xs[s])[f] = v;
    }
    __syncthreads();

    int u0 = blockIdx.y * TU + tid * 4;
    const float* W = kern + (size_t)c * (D_DIM * U_DIM) + u0;

    float acc[S_CHUNK][4];
    #pragma unroll
    for (int s = 0; s < S_CHUNK; ++s) {
        acc[s][0] = 0.f; acc[s][1] = 0.f; acc[s][2] = 0.f; acc[s][3] = 0.f;
    }

    for (int d4 = 0; d4 < D_DIM / 4; ++d4) {
        float4 w0 = *reinterpret_cast<const float4*>(W + (4 * d4 + 0) * U_DIM);
        float4 w1 = *reinterpret_cast<const float4*>(W + (4 * d4 + 1) * U_DIM);
        float4 w2 = *reinterpret_cast<const float4*>(W + (4 * d4 + 2) * U_DIM);
        float4 w3 = *reinterpret_cast<const float4*>(W + (4 * d4 + 3) * U_DIM);
        #pragma unroll
        for (int s = 0; s < S_CHUNK; ++s) {
            float4 xv = *reinterpret_cast<const float4*>(&xs[s][4 * d4]); // LDS broadcast
            acc[s][0] = fmaf(xv.x, w0.x, acc[s][0]);
            acc[s][0] = fmaf(xv.y, w1.x, acc[s][0]);
            acc[s][0] = fmaf(xv.z, w2.x, acc[s][0]);
            acc[s][0] = fmaf(xv.w, w3.x, acc[s][0]);
            acc[s][1] = fmaf(xv.x, w0.y, acc[s][1]);
            acc[s][1] = fmaf(xv.y, w1.y, acc[s][1]);
            acc[s][1] = fmaf(xv.z, w2.y, acc[s][1]);
            acc[s][1] = fmaf(xv.w, w3.y, acc[s][1]);
            acc[s][2] = fmaf(xv.x, w0.z, acc[s][2]);
            acc[s][2] = fmaf(xv.y, w1.z, acc[s][2]);
            acc[s][2] = fmaf(xv.z, w2.z, acc[s][2]);
            acc[s][2] = fmaf(xv.w, w3.z, acc[s][2]);
            acc[s][3] = fmaf(xv.x, w0.w, acc[s][3]);
            acc[s][3] = fmaf(xv.y, w1.w, acc[s][3]);
            acc[s][3] = fmaf(xv.z, w2.w, acc[s][3]);
            acc[s][3] = fmaf(xv.w, w3.w, acc[s][3]);
        }
    }

    float4 bb = *reinterpret_cast<const float4*>(bias + c * U_DIM + u0);
    #pragma unroll
    for (int s = 0; s < S_CHUNK; ++s) {   // static indices into acc (no scratch)
        if (s < len) {
            int b = sidx[s];
            float4 o;
            o.x = acc[s][0] + bb.x;
            o.y = acc[s][1] + bb.y;
            o.z = acc[s][2] + bb.z;
            o.w = acc[s][3] + bb.w;
            *reinterpret_cast<float4*>(out + (size_t)b * U_DIM + u0) = o;
        }
    }
}

// ---------------- launch ----------------

extern "C" void kernel_launch(void* const* d_in, const int* in_sizes, int n_in,
                              void* d_out, int out_size, void* d_ws, size_t ws_size,
                              hipStream_t stream) {
    const float* x    = (const float*)d_in[0];
    const int*   cls  = (const int*)d_in[1];
    const float* kern = (const float*)d_in[2];
    const float* bias = (const float*)d_in[3];
    float*       out  = (float*)d_out;

    int* ws           = (int*)d_ws;
    int* counts       = ws;          // 128
    int* cursor       = ws + 128;    // 128
    int* offsets      = ws + 256;    // 101
    int* total_chunks = ws + 384;    // 1
    int* order        = ws + 512;    // 2048
    int* chunk_cls    = ws + 2560;   // 360
    int* chunk_start  = ws + 2920;   // 360
    int* chunk_len    = ws + 3280;   // 360  (ends at 3640 ints = 14.6 KB)

    hipLaunchKernelGGL(k_init,    dim3(1), dim3(256), 0, stream, ws);
    hipLaunchKernelGGL(k_hist,    dim3((B_N + 255) / 256), dim3(256), 0, stream, cls, counts);
    hipLaunchKernelGGL(k_scan,    dim3(1), dim3(128), 0, stream, counts, offsets, total_chunks,
                       chunk_cls, chunk_start, chunk_len);
    hipLaunchKernelGGL(k_scatter, dim3((B_N + 255) / 256), dim3(256), 0, stream, cls, offsets,
                       cursor, order);
    hipLaunchKernelGGL(k_main,    dim3(MAX_CHUNKS, U_DIM / TU), dim3(64), 0, stream,
                       x, kern, bias, order, total_chunks, chunk_cls, chunk_start, chunk_len, out);
}